// Round 20
// baseline (270.359 us; speedup 1.0000x reference)
//
#include <hip/hip_runtime.h>
#include <hip/hip_bf16.h>
#include <stdint.h>

#define T_TOK 4096
#define DD 1024
#define EE 8
#define CC 512
#define FF 2752

typedef __attribute__((ext_vector_type(8))) short bf16x8;
typedef __attribute__((ext_vector_type(4))) float f32x4;
typedef __attribute__((ext_vector_type(4))) unsigned short us4;
typedef __attribute__((ext_vector_type(8))) unsigned short us8;

__device__ __forceinline__ float bf2f(unsigned short u) {
  union { float f; unsigned int i; } v; v.i = ((unsigned int)u) << 16; return v.f;
}
__device__ __forceinline__ unsigned short f2bf(float f) {
  union { float f; unsigned int i; } v; v.f = f;
  unsigned int r = v.i + 0x7fffu + ((v.i >> 16) & 1u);
  return (unsigned short)(r >> 16);
}

#define GLDS16(g, l) __builtin_amdgcn_global_load_lds( \
    (const __attribute__((address_space(1))) void*)(g), \
    (__attribute__((address_space(3))) void*)(l), 16, 0, 0)

// Verified swizzle (rounds 3-19) for bf16 fragment staging/reads.
#define STG_CHUNK(l) (((l & 3) ^ ((l >> 3) & 3)) * 8)
#define RD_OFF(fr, fq) ((fr) * 32 + (((fq) ^ (((fr) >> 1) & 3)) * 8))

#define BAR() do { asm volatile("" ::: "memory"); __builtin_amdgcn_s_barrier(); \
                   asm volatile("" ::: "memory"); } while (0)

__global__ void zero_me_k(float* me) { if (threadIdx.x < EE) me[threadIdx.x] = 0.0f; }

// ---------------- gating ----------------
__global__ void gate_k(const float* __restrict__ x, const float* __restrict__ wg,
                       const float* __restrict__ cw, const float* __restrict__ cbv,
                       int* __restrict__ idx, float* __restrict__ gatev,
                       float* __restrict__ coef, float* __restrict__ me_sum) {
  int tid = threadIdx.x, lane = tid & 63, wv = tid >> 6;
  int t = blockIdx.x * 4 + wv;
  const float* xr = x + (long)t * DD;
  float acc[EE] = {0,0,0,0,0,0,0,0};
  float c0 = 0.0f, c1 = 0.0f;
  for (int d = lane; d < DD; d += 64) {
    float xv = xr[d];
#pragma unroll
    for (int e = 0; e < EE; ++e) acc[e] += xv * wg[d * EE + e];
    c0 += xv * cw[d * 2 + 0];
    c1 += xv * cw[d * 2 + 1];
  }
#pragma unroll
  for (int o = 32; o > 0; o >>= 1) {
#pragma unroll
    for (int e = 0; e < EE; ++e) acc[e] += __shfl_xor(acc[e], o);
    c0 += __shfl_xor(c0, o);
    c1 += __shfl_xor(c1, o);
  }
  __shared__ float sme[EE];
  if (tid < EE) sme[tid] = 0.0f;
  __syncthreads();
  if (lane == 0) {
    float m = acc[0]; int am = 0;
#pragma unroll
    for (int e = 1; e < EE; ++e) if (acc[e] > m) { m = acc[e]; am = e; }
    float g[EE]; float s = 0.0f;
#pragma unroll
    for (int e = 0; e < EE; ++e) { g[e] = __expf(acc[e] - m); s += g[e]; }
    float inv = 1.0f / s;
    idx[t] = am;
    gatev[t] = g[am] * inv;
#pragma unroll
    for (int e = 0; e < EE; ++e) atomicAdd(&sme[e], g[e] * inv);
    float l0 = c0 + cbv[0], l1 = c1 + cbv[1];
    float mm = fmaxf(l0, l1);
    float e0 = __expf(l0 - mm), e1 = __expf(l1 - mm);
    float is = 1.0f / (e0 + e1);
    coef[t * 2 + 0] = e0 * is;
    coef[t * 2 + 1] = e1 * is;
  }
  __syncthreads();
  if (tid < EE) atomicAdd(&me_sum[tid], sme[tid]);
}

// ---------------- capacity scan ----------------
__global__ void scan_k(const int* __restrict__ idx, const float* __restrict__ me_sum,
                       int* __restrict__ slot, int* __restrict__ tok,
                       float* __restrict__ out_tail) {
  __shared__ int sidx[T_TOK];
  __shared__ int counts[EE];
  int tid = threadIdx.x;
  for (int i = tid; i < T_TOK; i += 512) sidx[i] = idx[i];
  __syncthreads();
  int e = tid >> 6, lane = tid & 63;
  int base = 0;
  for (int it = 0; it < T_TOK / 64; ++it) {
    int t = it * 64 + lane;
    bool f = (sidx[t] == e);
    unsigned long long m = __ballot(f);
    if (f) {
      int loc = base + __popcll(m & ((1ull << lane) - 1ull));
      slot[t] = (loc < CC) ? loc : -1;
      if (loc < CC) tok[e * CC + loc] = t;
    }
    base += __popcll(m);
  }
  if (lane == 0) counts[e] = base;
  __syncthreads();
  int filled = min(counts[e], CC);
  for (int c = filled + lane; c < CC; c += 64) tok[e * CC + c] = -1;
  if (tid == 0) {
    float la = 0.0f;
    for (int i = 0; i < EE; ++i) la += me_sum[i] * (float)counts[i];
    la *= (float)EE / ((float)T_TOK * (float)T_TOK);
    out_tail[0] = la;
    for (int i = 0; i < EE; ++i) out_tail[1 + i] = (float)counts[i];
  }
}

// ---------------- gather + bf16 convert ----------------
__global__ void gather_k(const float* __restrict__ x, const int* __restrict__ tok,
                         unsigned short* __restrict__ xb, unsigned short* __restrict__ xe) {
  int r = blockIdx.x, tid = threadIdx.x;
  int d = tid * 4;
  if (r < T_TOK) {
    float4 v = *(const float4*)(x + (long)r * DD + d);
    us4 o; o.x = f2bf(v.x); o.y = f2bf(v.y); o.z = f2bf(v.z); o.w = f2bf(v.w);
    *(us4*)(xb + (long)r * DD + d) = o;
  } else {
    int s = r - T_TOK;
    int t = tok[s];
    us4 o = {0, 0, 0, 0};
    if (t >= 0) {
      float4 v = *(const float4*)(x + (long)t * DD + d);
      o.x = f2bf(v.x); o.y = f2bf(v.y); o.z = f2bf(v.z); o.w = f2bf(v.w);
    }
    *(us4*)(xe + (long)s * DD + d) = o;
  }
}

// ---------------- fused GEMM1 + epilogue w2-transpose ------------
// 704 blocks. K-loop + C-write are r12/r18-verified. Epilogue: each block
// transposes 10 tiles (2 at a time x 5 passes) of w2/rw2 -> bf16, issuing
// the 146 MB of transpose HBM traffic while other blocks' MFMA runs.
// Before LDS reuse: s_waitcnt vmcnt(0) + BAR drains the K-loop's stale
// wrapped prefetch glds (they target Lc and would corrupt smf otherwise).
__global__ __launch_bounds__(512, 2)
void gemm1_k(const unsigned short* __restrict__ xcat,
             const float* __restrict__ w1, const float* __restrict__ w3,
             const float* __restrict__ rw1, const float* __restrict__ rw3,
             unsigned short* __restrict__ Hcat,
             const float* __restrict__ w2, const float* __restrict__ rw2,
             unsigned short* __restrict__ w2t, unsigned short* __restrict__ rw2t) {
  __shared__ __align__(16) char Lc[147456];   // 144 KB
  int lin = blockIdx.x;
  int tid = threadIdx.x;

  int work = (lin & 7) * 88 + (lin >> 3);     // 704 = 8 * 88
  int mtile, ntile;
  if (work < 352) {
    int e = work / 44, r = work - e * 44;
    ntile = r >> 1;
    mtile = e * 2 + (r & 1);
  } else {
    int q = work - 352;
    ntile = q >> 4;
    mtile = 16 + (q & 15);
  }
  const unsigned short* A = xcat + (size_t)mtile * 256 * DD;
  const float *B1, *B3;
  if (mtile < 16) { int e = mtile >> 1; B1 = w1 + (size_t)e * DD * FF; B3 = w3 + (size_t)e * DD * FF; }
  else { B1 = rw1; B3 = rw3; }
  unsigned short* H = Hcat + (size_t)mtile * 256 * FF;
  int n0 = ntile * 128;

  const unsigned short* ldsS = (const unsigned short*)Lc;

  int l = tid & 63, w = tid >> 6;
  int wm = w >> 2, wn = w & 3;               // wm2 x wn4
  int fr = l & 15, fq = l >> 4;
  int srow = l >> 2, soff = STG_CHUNK(l);
  int rdo = RD_OFF(fr, fq);

  const unsigned short* gA0 = A + (size_t)(w * 16 + srow) * DD + soff;
  const unsigned short* gA1 = A + (size_t)((8 + w) * 16 + srow) * DD + soff;
  int lrow = l >> 5;
  int kl0 = 2 * w + lrow;
  int kl1 = 16 + 2 * w + lrow;
  int cs0 = (l & 31) ^ (((kl0 >> 3) & 1) << 2);
  int cs1 = (l & 31) ^ (((kl1 >> 3) & 1) << 2);
  int nn0 = n0 + 4 * cs0; if (nn0 >= FF) nn0 = 0;
  int nn1 = n0 + 4 * cs1; if (nn1 >= FF) nn1 = 0;
  const float* gB1a = B1 + (size_t)kl0 * FF + nn0;
  const float* gB1b = B1 + (size_t)kl1 * FF + nn1;
  const float* gB3a = B3 + (size_t)kl0 * FF + nn0;
  const float* gB3b = B3 + (size_t)kl1 * FF + nn1;

  int cb2[2][4];
#pragma unroll
  for (int ni = 0; ni < 2; ++ni) {
    int base = fq * 4096 + ((((wn * 2 + ni) * 64 + fr * 4)) ^ ((fq & 1) << 6));
#pragma unroll
    for (int p = 0; p < 4; ++p) cb2[ni][p] = base + p * 1024;
  }

#define STG1(bb, hw) do { size_t ka = (size_t)(hw) * 32; size_t kb = ka * FF;   \
    GLDS16(gA0 + ka, Lc + (bb) * 16384 + w * 1024);                             \
    GLDS16(gA1 + ka, Lc + (bb) * 16384 + (8 + w) * 1024);                       \
    GLDS16(gB1a + kb, Lc + 49152 + (bb) * 16384 + w * 1024);                    \
    GLDS16(gB1b + kb, Lc + 49152 + (bb) * 16384 + (8 + w) * 1024);              \
    GLDS16(gB3a + kb, Lc + 98304 + (bb) * 16384 + w * 1024);                    \
    GLDS16(gB3b + kb, Lc + 98304 + (bb) * 16384 + (8 + w) * 1024); } while (0)

  f32x4 acc1[8][2] = {};
  f32x4 acc3[8][2] = {};

  const int HN = 32;
  STG1(0, 0);
  STG1(1, 1);

  for (int h = 0; h < HN; ++h) {
    int buf = h % 3;
    int hw = h + 2; if (hw >= HN) hw -= HN;
    int bufw = (buf + 2) % 3;

    asm volatile("s_waitcnt vmcnt(6)" ::: "memory");
    BAR();
    STG1(bufw, hw);

    const char* Bb1 = Lc + 49152 + buf * 16384;
    const char* Bb3 = Lc + 98304 + buf * 16384;
    bf16x8 af[8];
#pragma unroll
    for (int mi = 0; mi < 8; ++mi)
      af[mi] = *(const bf16x8*)(ldsS + buf * 8192 + (wm * 8 + mi) * 512 + rdo);

    {
      float fb[2][8];
#pragma unroll
      for (int ni = 0; ni < 2; ++ni)
#pragma unroll
        for (int p = 0; p < 4; ++p) {
          const char* bp = Bb1 + cb2[ni][p];
          fb[ni][2 * p]     = *(const float*)(bp);
          fb[ni][2 * p + 1] = *(const float*)(bp + 512);
        }
      __builtin_amdgcn_s_setprio(1);
#pragma unroll
      for (int ni = 0; ni < 2; ++ni) {
        union { bf16x8 h; unsigned int u[4]; } bu;
#pragma unroll
        for (int p = 0; p < 4; ++p)
          asm("v_cvt_pk_bf16_f32 %0, %1, %2" : "=v"(bu.u[p]) : "v"(fb[ni][2 * p]), "v"(fb[ni][2 * p + 1]));
#pragma unroll
        for (int mi = 0; mi < 8; ++mi)
          acc1[mi][ni] = __builtin_amdgcn_mfma_f32_16x16x32_bf16(af[mi], bu.h, acc1[mi][ni], 0, 0, 0);
      }
      __builtin_amdgcn_s_setprio(0);
    }
    {
      float fb[2][8];
#pragma unroll
      for (int ni = 0; ni < 2; ++ni)
#pragma unroll
        for (int p = 0; p < 4; ++p) {
          const char* bp = Bb3 + cb2[ni][p];
          fb[ni][2 * p]     = *(const float*)(bp);
          fb[ni][2 * p + 1] = *(const float*)(bp + 512);
        }
      __builtin_amdgcn_s_setprio(1);
#pragma unroll
      for (int ni = 0; ni < 2; ++ni) {
        union { bf16x8 h; unsigned int u[4]; } bu;
#pragma unroll
        for (int p = 0; p < 4; ++p)
          asm("v_cvt_pk_bf16_f32 %0, %1, %2" : "=v"(bu.u[p]) : "v"(fb[ni][2 * p]), "v"(fb[ni][2 * p + 1]));
#pragma unroll
        for (int mi = 0; mi < 8; ++mi)
          acc3[mi][ni] = __builtin_amdgcn_mfma_f32_16x16x32_bf16(af[mi], bu.h, acc3[mi][ni], 0, 0, 0);
      }
      __builtin_amdgcn_s_setprio(0);
    }
  }
#undef STG1

  // ---- C-write (registers/global only) ----
#pragma unroll
  for (int mi = 0; mi < 8; ++mi)
#pragma unroll
    for (int ni = 0; ni < 2; ++ni)
#pragma unroll
      for (int r = 0; r < 4; ++r) {
        int gm = wm * 128 + mi * 16 + fq * 4 + r;
        int gn = n0 + (wn * 2 + ni) * 16 + fr;
        if (gn < FF) {
          float v1 = acc1[mi][ni][r], v3 = acc3[mi][ni][r];
          float h = v1 / (1.0f + __expf(-v1)) * v3;
          H[(size_t)gm * FF + gn] = f2bf(h);
        }
      }

  // ---- epilogue transpose: 10 tiles (2 x 5 passes) ----
  asm volatile("s_waitcnt vmcnt(0)" ::: "memory");   // drain stale K-loop glds
  BAR();                                              // LDS safe to reuse
  int half = tid >> 8, t = tid & 255;
  int rr = t >> 4, c4 = (t & 15) * 4;
  float* smf = (float*)(Lc + half * 17152);           // 64*65*4 B used per half
  for (int pass = 0; pass < 5; ++pass) {
    int tile = lin * 10 + pass * 2 + half;
    bool valid = (tile < 6192);                       // 9 slabs * 688 tiles
    int z = 0, y = 0, xb = 0;
    const float* tin = rw2;
    unsigned short* tout = rw2t;
    if (valid) {
      z = tile / 688;
      int rem = tile - z * 688;
      y = rem >> 4; xb = rem & 15;
      if (z < EE) { tin = w2 + (size_t)z * FF * DD; tout = w2t + (size_t)z * DD * FF; }
    }
    int cbx = xb * 64, rb = y * 64;
    if (valid) {
#pragma unroll
      for (int i = 0; i < 4; ++i) {
        int r = rr + i * 16;
        float4 v = *(const float4*)(tin + (size_t)(rb + r) * DD + cbx + c4);
        smf[(c4 + 0) * 65 + r] = v.x;
        smf[(c4 + 1) * 65 + r] = v.y;
        smf[(c4 + 2) * 65 + r] = v.z;
        smf[(c4 + 3) * 65 + r] = v.w;
      }
    }
    BAR();
    if (valid) {
#pragma unroll
      for (int j = 0; j < 2; ++j) {
        int idx = t + j * 256;
        int g = idx & 7, c = idx >> 3;
        int r8 = g * 8;
        us8 o;
#pragma unroll
        for (int k = 0; k < 8; ++k) o[k] = f2bf(smf[c * 65 + r8 + k]);
        *(us8*)(tout + (size_t)(cbx + c) * FF + rb + r8) = o;
      }
    }
    BAR();
  }
}

// ---------------- GEMM2: Y = H @ W2 (r17 single-barrier) ---------
__global__ __launch_bounds__(512, 2)
void gemm2_k(const unsigned short* __restrict__ Hcat,
             const unsigned short* __restrict__ w2t, const unsigned short* __restrict__ rw2t,
             unsigned short* __restrict__ Ycat) {
  int lin = blockIdx.x;
  int work = (lin & 7) * 32 + (lin >> 3);    // 256 = 8 * 32
  int mtile, ntile;
  if (work < 128) {
    int e = work >> 4, r = work & 15;
    ntile = r >> 1;
    mtile = e * 2 + (r & 1);
  } else {
    int q = work - 128;
    ntile = q >> 4;
    mtile = 16 + (q & 15);
  }
  const unsigned short* A = Hcat + (size_t)mtile * 256 * FF;
  const unsigned short* B = (mtile < 16) ? (w2t + (size_t)(mtile >> 1) * (size_t)DD * FF) : rw2t;
  unsigned short* Y = Ycat + (size_t)mtile * 256 * DD;
  int n0 = ntile * 128;

  __shared__ __align__(16) unsigned short lds[73728];   // 144 KB
  char* Lc = (char*)lds;

  int tid = threadIdx.x, l = tid & 63, w = tid >> 6;
  int wm = w >> 1, wn = w & 1;
  int fr = l & 15, fq = l >> 4;
  int srow = l >> 2, soff = STG_CHUNK(l);
  int rdo = RD_OFF(fr, fq);

  const unsigned short* gA0 = A + (size_t)(w * 16 + srow) * FF + soff;
  const unsigned short* gA1 = A + (size_t)((8 + w) * 16 + srow) * FF + soff;
  const unsigned short* gB  = B + (size_t)(n0 + w * 16 + srow) * FF + soff;

#define STG2(bb, kk) do {                                          \
    GLDS16(gA0 + (kk), Lc + (bb) * 16384 + w * 1024);              \
    GLDS16(gA1 + (kk), Lc + (bb) * 16384 + (8 + w) * 1024);        \
    GLDS16(gB  + (kk), Lc + 98304 + (bb) * 8192 + w * 1024); } while (0)

  f32x4 acc[4][4] = {};

  const int HN = 86;   // halves (K=2752 / 32)
#pragma unroll
  for (int hh = 0; hh < 5; ++hh) STG2(hh, hh * 32);

  int b = 0;
#pragma unroll 2
  for (int h = 0; h < HN; ++h) {
    int bn = b ? b - 1 : 5;              // (h+5) % 6
    int hw = h + 5; if (hw >= HN) hw -= HN;
    int kk = hw * 32;
    bf16x8 af[4], bf[4];

    asm volatile("s_waitcnt vmcnt(12)" ::: "memory");   // half h landed
    BAR();
    STG2(bn, kk);                                       // stage h+5
#pragma unroll
    for (int mi = 0; mi < 4; ++mi)
      af[mi] = *(const bf16x8*)(lds + b * 8192 + (wm * 4 + mi) * 512 + rdo);
#pragma unroll
    for (int ni = 0; ni < 4; ++ni)
      bf[ni] = *(const bf16x8*)(lds + 49152 + b * 4096 + (wn * 4 + ni) * 512 + rdo);
    __builtin_amdgcn_s_setprio(1);
#pragma unroll
    for (int mi = 0; mi < 4; ++mi)
#pragma unroll
      for (int ni = 0; ni < 4; ++ni)
        acc[mi][ni] = __builtin_amdgcn_mfma_f32_16x16x32_bf16(af[mi], bf[ni], acc[mi][ni], 0, 0, 0);
    __builtin_amdgcn_s_setprio(0);

    ++b; if (b == 6) b = 0;
  }
#undef STG2

#pragma unroll
  for (int mi = 0; mi < 4; ++mi)
#pragma unroll
    for (int ni = 0; ni < 4; ++ni)
#pragma unroll
      for (int r = 0; r < 4; ++r) {
        int gm = wm * 64 + mi * 16 + fq * 4 + r;
        int gn = n0 + wn * 64 + ni * 16 + fr;
        Y[(size_t)gm * DD + gn] = f2bf(acc[mi][ni][r]);
      }
}

// ---------------- combine ----------------------------------------
__global__ void combine_k(const unsigned short* __restrict__ Ye, const unsigned short* __restrict__ Yr,
                          const int* __restrict__ idx, const int* __restrict__ slot,
                          const float* __restrict__ gatev, const float* __restrict__ coef,
                          float* __restrict__ out) {
  int t = blockIdx.x, tid = threadIdx.x;
  int d = tid * 4;
  float c0 = coef[t * 2], c1 = coef[t * 2 + 1];
  int s = slot[t];
  float g = gatev[t] * c0;
  us4 vr = *(const us4*)(Yr + (size_t)t * DD + d);
  float4 o;
  if (s >= 0) {
    us4 ve = *(const us4*)(Ye + ((size_t)idx[t] * CC + s) * DD + d);
    o.x = g * bf2f(ve.x) + c1 * bf2f(vr.x);
    o.y = g * bf2f(ve.y) + c1 * bf2f(vr.y);
    o.z = g * bf2f(ve.z) + c1 * bf2f(vr.z);
    o.w = g * bf2f(ve.w) + c1 * bf2f(vr.w);
  } else {
    o.x = c1 * bf2f(vr.x);
    o.y = c1 * bf2f(vr.y);
    o.z = c1 * bf2f(vr.z);
    o.w = c1 * bf2f(vr.w);
  }
  *(float4*)(out + (size_t)t * DD + d) = o;
}

// ---------------- launch -----------------------------------------
extern "C" void kernel_launch(void* const* d_in, const int* in_sizes, int n_in,
                              void* d_out, int out_size, void* d_ws, size_t ws_size,
                              hipStream_t stream) {
  const float* x   = (const float*)d_in[0];
  const float* wg  = (const float*)d_in[1];
  const float* w1  = (const float*)d_in[2];
  const float* w3  = (const float*)d_in[3];
  const float* w2  = (const float*)d_in[4];
  const float* rw1 = (const float*)d_in[5];
  const float* rw3 = (const float*)d_in[6];
  const float* rw2 = (const float*)d_in[7];
  const float* cw  = (const float*)d_in[8];
  const float* cbv = (const float*)d_in[9];
  float* out = (float*)d_out;

  char* ws = (char*)d_ws;
  size_t o = 0;
  auto alloc = [&](size_t bytes) -> char* {
    char* p = ws + o; o = (o + bytes + 255) & ~(size_t)255; return p;
  };
  unsigned short* w2t  = (unsigned short*)alloc((size_t)EE * DD * FF * 2);
  unsigned short* rw2t = (unsigned short*)alloc((size_t)DD * FF * 2);
  unsigned short* xe   = (unsigned short*)alloc((size_t)T_TOK * DD * 2);
  unsigned short* xb   = (unsigned short*)alloc((size_t)T_TOK * DD * 2);
  unsigned short* He   = (unsigned short*)alloc((size_t)T_TOK * FF * 2);
  unsigned short* Hr   = (unsigned short*)alloc((size_t)T_TOK * FF * 2);
  unsigned short* Ye   = (unsigned short*)alloc((size_t)T_TOK * DD * 2);
  unsigned short* Yr   = (unsigned short*)alloc((size_t)T_TOK * DD * 2);
  int*   idxp  = (int*)alloc(T_TOK * 4);
  float* gatev = (float*)alloc(T_TOK * 4);
  int*   slotp = (int*)alloc(T_TOK * 4);
  int*   tokp  = (int*)alloc(EE * CC * 4);
  float* coefp = (float*)alloc(T_TOK * 2 * 4);
  float* mep   = (float*)alloc(256);
  if (o > ws_size) return;

  zero_me_k<<<1, 64, 0, stream>>>(mep);
  gate_k<<<T_TOK / 4, 256, 0, stream>>>(x, wg, cw, cbv, idxp, gatev, coefp, mep);
  scan_k<<<1, 512, 0, stream>>>(idxp, mep, slotp, tokp, out + (size_t)T_TOK * DD);
  gather_k<<<2 * T_TOK, 256, 0, stream>>>(x, tokp, xb, xe);
  gemm1_k<<<704, 512, 0, stream>>>(xe, w1, w3, rw1, rw3, He, w2, rw2, w2t, rw2t);
  gemm2_k<<<256, 512, 0, stream>>>(He, w2t, rw2t, Ye);
  combine_k<<<T_TOK, 256, 0, stream>>>(Ye, Yr, idxp, slotp, gatev, coefp, out);
}

// Round 21
// 255.370 us; speedup vs baseline: 1.0587x; 1.0587x over previous
//
#include <hip/hip_runtime.h>
#include <hip/hip_bf16.h>
#include <stdint.h>

#define T_TOK 4096
#define DD 1024
#define EE 8
#define CC 512
#define FF 2752

typedef __attribute__((ext_vector_type(8))) short bf16x8;
typedef __attribute__((ext_vector_type(4))) float f32x4;
typedef __attribute__((ext_vector_type(4))) unsigned short us4;
typedef __attribute__((ext_vector_type(8))) unsigned short us8;

__device__ __forceinline__ float bf2f(unsigned short u) {
  union { float f; unsigned int i; } v; v.i = ((unsigned int)u) << 16; return v.f;
}
__device__ __forceinline__ unsigned short f2bf(float f) {
  union { float f; unsigned int i; } v; v.f = f;
  unsigned int r = v.i + 0x7fffu + ((v.i >> 16) & 1u);
  return (unsigned short)(r >> 16);
}

#define GLDS16(g, l) __builtin_amdgcn_global_load_lds( \
    (const __attribute__((address_space(1))) void*)(g), \
    (__attribute__((address_space(3))) void*)(l), 16, 0, 0)

// Verified swizzle (rounds 3-20) for bf16 fragment staging/reads.
#define STG_CHUNK(l) (((l & 3) ^ ((l >> 3) & 3)) * 8)
#define RD_OFF(fr, fq) ((fr) * 32 + (((fq) ^ (((fr) >> 1) & 3)) * 8))

#define BAR() do { asm volatile("" ::: "memory"); __builtin_amdgcn_s_barrier(); \
                   asm volatile("" ::: "memory"); } while (0)

__global__ void zero_me_k(float* me) { if (threadIdx.x < EE) me[threadIdx.x] = 0.0f; }

// ---------------- gating ----------------
__global__ void gate_k(const float* __restrict__ x, const float* __restrict__ wg,
                       const float* __restrict__ cw, const float* __restrict__ cbv,
                       int* __restrict__ idx, float* __restrict__ gatev,
                       float* __restrict__ coef, float* __restrict__ me_sum) {
  int tid = threadIdx.x, lane = tid & 63, wv = tid >> 6;
  int t = blockIdx.x * 4 + wv;
  const float* xr = x + (long)t * DD;
  float acc[EE] = {0,0,0,0,0,0,0,0};
  float c0 = 0.0f, c1 = 0.0f;
  for (int d = lane; d < DD; d += 64) {
    float xv = xr[d];
#pragma unroll
    for (int e = 0; e < EE; ++e) acc[e] += xv * wg[d * EE + e];
    c0 += xv * cw[d * 2 + 0];
    c1 += xv * cw[d * 2 + 1];
  }
#pragma unroll
  for (int o = 32; o > 0; o >>= 1) {
#pragma unroll
    for (int e = 0; e < EE; ++e) acc[e] += __shfl_xor(acc[e], o);
    c0 += __shfl_xor(c0, o);
    c1 += __shfl_xor(c1, o);
  }
  __shared__ float sme[EE];
  if (tid < EE) sme[tid] = 0.0f;
  __syncthreads();
  if (lane == 0) {
    float m = acc[0]; int am = 0;
#pragma unroll
    for (int e = 1; e < EE; ++e) if (acc[e] > m) { m = acc[e]; am = e; }
    float g[EE]; float s = 0.0f;
#pragma unroll
    for (int e = 0; e < EE; ++e) { g[e] = __expf(acc[e] - m); s += g[e]; }
    float inv = 1.0f / s;
    idx[t] = am;
    gatev[t] = g[am] * inv;
#pragma unroll
    for (int e = 0; e < EE; ++e) atomicAdd(&sme[e], g[e] * inv);
    float l0 = c0 + cbv[0], l1 = c1 + cbv[1];
    float mm = fmaxf(l0, l1);
    float e0 = __expf(l0 - mm), e1 = __expf(l1 - mm);
    float is = 1.0f / (e0 + e1);
    coef[t * 2 + 0] = e0 * is;
    coef[t * 2 + 1] = e1 * is;
  }
  __syncthreads();
  if (tid < EE) atomicAdd(&me_sum[tid], sme[tid]);
}

// ---------------- capacity scan ----------------
__global__ void scan_k(const int* __restrict__ idx, const float* __restrict__ me_sum,
                       int* __restrict__ slot, int* __restrict__ tok,
                       float* __restrict__ out_tail) {
  __shared__ int sidx[T_TOK];
  __shared__ int counts[EE];
  int tid = threadIdx.x;
  for (int i = tid; i < T_TOK; i += 512) sidx[i] = idx[i];
  __syncthreads();
  int e = tid >> 6, lane = tid & 63;
  int base = 0;
  for (int it = 0; it < T_TOK / 64; ++it) {
    int t = it * 64 + lane;
    bool f = (sidx[t] == e);
    unsigned long long m = __ballot(f);
    if (f) {
      int loc = base + __popcll(m & ((1ull << lane) - 1ull));
      slot[t] = (loc < CC) ? loc : -1;
      if (loc < CC) tok[e * CC + loc] = t;
    }
    base += __popcll(m);
  }
  if (lane == 0) counts[e] = base;
  __syncthreads();
  int filled = min(counts[e], CC);
  for (int c = filled + lane; c < CC; c += 64) tok[e * CC + c] = -1;
  if (tid == 0) {
    float la = 0.0f;
    for (int i = 0; i < EE; ++i) la += me_sum[i] * (float)counts[i];
    la *= (float)EE / ((float)T_TOK * (float)T_TOK);
    out_tail[0] = la;
    for (int i = 0; i < EE; ++i) out_tail[1 + i] = (float)counts[i];
  }
}

// ---------------- gather + bf16 convert ----------------
__global__ void gather_k(const float* __restrict__ x, const int* __restrict__ tok,
                         unsigned short* __restrict__ xb, unsigned short* __restrict__ xe) {
  int r = blockIdx.x, tid = threadIdx.x;
  int d = tid * 4;
  if (r < T_TOK) {
    float4 v = *(const float4*)(x + (long)r * DD + d);
    us4 o; o.x = f2bf(v.x); o.y = f2bf(v.y); o.z = f2bf(v.z); o.w = f2bf(v.w);
    *(us4*)(xb + (long)r * DD + d) = o;
  } else {
    int s = r - T_TOK;
    int t = tok[s];
    us4 o = {0, 0, 0, 0};
    if (t >= 0) {
      float4 v = *(const float4*)(x + (long)t * DD + d);
      o.x = f2bf(v.x); o.y = f2bf(v.y); o.z = f2bf(v.z); o.w = f2bf(v.w);
    }
    *(us4*)(xe + (long)s * DD + d) = o;
  }
}

// ---------------- GEMM1 (r12/r18 verified, best) -----------------
__global__ __launch_bounds__(512, 2)
void gemm1_k(const unsigned short* __restrict__ xcat,
             const float* __restrict__ w1, const float* __restrict__ w3,
             const float* __restrict__ rw1, const float* __restrict__ rw3,
             unsigned short* __restrict__ Hcat) {
  int lin = blockIdx.x;
  int work = (lin & 7) * 88 + (lin >> 3);     // 704 = 8 * 88
  int mtile, ntile;
  if (work < 352) {
    int e = work / 44, r = work - e * 44;
    ntile = r >> 1;
    mtile = e * 2 + (r & 1);
  } else {
    int q = work - 352;
    ntile = q >> 4;
    mtile = 16 + (q & 15);
  }
  const unsigned short* A = xcat + (size_t)mtile * 256 * DD;
  const float *B1, *B3;
  if (mtile < 16) { int e = mtile >> 1; B1 = w1 + (size_t)e * DD * FF; B3 = w3 + (size_t)e * DD * FF; }
  else { B1 = rw1; B3 = rw3; }
  unsigned short* H = Hcat + (size_t)mtile * 256 * FF;
  int n0 = ntile * 128;

  __shared__ __align__(16) char Lc[147456];   // 144 KB
  const unsigned short* ldsS = (const unsigned short*)Lc;

  int tid = threadIdx.x, l = tid & 63, w = tid >> 6;
  int wm = w >> 2, wn = w & 3;               // wm2 x wn4
  int fr = l & 15, fq = l >> 4;
  int srow = l >> 2, soff = STG_CHUNK(l);
  int rdo = RD_OFF(fr, fq);

  const unsigned short* gA0 = A + (size_t)(w * 16 + srow) * DD + soff;
  const unsigned short* gA1 = A + (size_t)((8 + w) * 16 + srow) * DD + soff;
  int lrow = l >> 5;
  int kl0 = 2 * w + lrow;
  int kl1 = 16 + 2 * w + lrow;
  int cs0 = (l & 31) ^ (((kl0 >> 3) & 1) << 2);
  int cs1 = (l & 31) ^ (((kl1 >> 3) & 1) << 2);
  int nn0 = n0 + 4 * cs0; if (nn0 >= FF) nn0 = 0;
  int nn1 = n0 + 4 * cs1; if (nn1 >= FF) nn1 = 0;
  const float* gB1a = B1 + (size_t)kl0 * FF + nn0;
  const float* gB1b = B1 + (size_t)kl1 * FF + nn1;
  const float* gB3a = B3 + (size_t)kl0 * FF + nn0;
  const float* gB3b = B3 + (size_t)kl1 * FF + nn1;

  int cb2[2][4];
#pragma unroll
  for (int ni = 0; ni < 2; ++ni) {
    int base = fq * 4096 + ((((wn * 2 + ni) * 64 + fr * 4)) ^ ((fq & 1) << 6));
#pragma unroll
    for (int p = 0; p < 4; ++p) cb2[ni][p] = base + p * 1024;
  }

#define STG1(bb, hw) do { size_t ka = (size_t)(hw) * 32; size_t kb = ka * FF;   \
    GLDS16(gA0 + ka, Lc + (bb) * 16384 + w * 1024);                             \
    GLDS16(gA1 + ka, Lc + (bb) * 16384 + (8 + w) * 1024);                       \
    GLDS16(gB1a + kb, Lc + 49152 + (bb) * 16384 + w * 1024);                    \
    GLDS16(gB1b + kb, Lc + 49152 + (bb) * 16384 + (8 + w) * 1024);              \
    GLDS16(gB3a + kb, Lc + 98304 + (bb) * 16384 + w * 1024);                    \
    GLDS16(gB3b + kb, Lc + 98304 + (bb) * 16384 + (8 + w) * 1024); } while (0)

  f32x4 acc1[8][2] = {};
  f32x4 acc3[8][2] = {};

  const int HN = 32;
  STG1(0, 0);
  STG1(1, 1);

  for (int h = 0; h < HN; ++h) {
    int buf = h % 3;
    int hw = h + 2; if (hw >= HN) hw -= HN;
    int bufw = (buf + 2) % 3;

    asm volatile("s_waitcnt vmcnt(6)" ::: "memory");
    BAR();
    STG1(bufw, hw);

    const char* Bb1 = Lc + 49152 + buf * 16384;
    const char* Bb3 = Lc + 98304 + buf * 16384;
    bf16x8 af[8];
#pragma unroll
    for (int mi = 0; mi < 8; ++mi)
      af[mi] = *(const bf16x8*)(ldsS + buf * 8192 + (wm * 8 + mi) * 512 + rdo);

    {
      float fb[2][8];
#pragma unroll
      for (int ni = 0; ni < 2; ++ni)
#pragma unroll
        for (int p = 0; p < 4; ++p) {
          const char* bp = Bb1 + cb2[ni][p];
          fb[ni][2 * p]     = *(const float*)(bp);
          fb[ni][2 * p + 1] = *(const float*)(bp + 512);
        }
      __builtin_amdgcn_s_setprio(1);
#pragma unroll
      for (int ni = 0; ni < 2; ++ni) {
        union { bf16x8 h; unsigned int u[4]; } bu;
#pragma unroll
        for (int p = 0; p < 4; ++p)
          asm("v_cvt_pk_bf16_f32 %0, %1, %2" : "=v"(bu.u[p]) : "v"(fb[ni][2 * p]), "v"(fb[ni][2 * p + 1]));
#pragma unroll
        for (int mi = 0; mi < 8; ++mi)
          acc1[mi][ni] = __builtin_amdgcn_mfma_f32_16x16x32_bf16(af[mi], bu.h, acc1[mi][ni], 0, 0, 0);
      }
      __builtin_amdgcn_s_setprio(0);
    }
    {
      float fb[2][8];
#pragma unroll
      for (int ni = 0; ni < 2; ++ni)
#pragma unroll
        for (int p = 0; p < 4; ++p) {
          const char* bp = Bb3 + cb2[ni][p];
          fb[ni][2 * p]     = *(const float*)(bp);
          fb[ni][2 * p + 1] = *(const float*)(bp + 512);
        }
      __builtin_amdgcn_s_setprio(1);
#pragma unroll
      for (int ni = 0; ni < 2; ++ni) {
        union { bf16x8 h; unsigned int u[4]; } bu;
#pragma unroll
        for (int p = 0; p < 4; ++p)
          asm("v_cvt_pk_bf16_f32 %0, %1, %2" : "=v"(bu.u[p]) : "v"(fb[ni][2 * p]), "v"(fb[ni][2 * p + 1]));
#pragma unroll
        for (int mi = 0; mi < 8; ++mi)
          acc3[mi][ni] = __builtin_amdgcn_mfma_f32_16x16x32_bf16(af[mi], bu.h, acc3[mi][ni], 0, 0, 0);
      }
      __builtin_amdgcn_s_setprio(0);
    }
  }
#undef STG1

#pragma unroll
  for (int mi = 0; mi < 8; ++mi)
#pragma unroll
    for (int ni = 0; ni < 2; ++ni)
#pragma unroll
      for (int r = 0; r < 4; ++r) {
        int gm = wm * 128 + mi * 16 + fq * 4 + r;
        int gn = n0 + (wn * 2 + ni) * 16 + fr;
        if (gn < FF) {
          float v1 = acc1[mi][ni][r], v3 = acc3[mi][ni][r];
          float h = v1 / (1.0f + __expf(-v1)) * v3;
          H[(size_t)gm * FF + gn] = f2bf(h);
        }
      }
}

// ---------------- GEMM2: Y = H @ W2, direct-f32 W2 ---------------
// Structural clone of gemm1's verified f32-B path: W2 is [F][D]=[k][n]
// row-major, exactly w1's layout. wm2 x wn4, 3-buf ring (96 KB), single
// B phase, HN=86, vmcnt(4) (4 glds/stage). No transpose pre-pass needed.
__global__ __launch_bounds__(512, 2)
void gemm2_k(const unsigned short* __restrict__ Hcat,
             const float* __restrict__ w2, const float* __restrict__ rw2,
             unsigned short* __restrict__ Ycat) {
  int lin = blockIdx.x;
  int work = (lin & 7) * 32 + (lin >> 3);    // 256 = 8 * 32
  int mtile, ntile;
  if (work < 128) {
    int e = work >> 4, r = work & 15;
    ntile = r >> 1;
    mtile = e * 2 + (r & 1);
  } else {
    int q = work - 128;
    ntile = q >> 4;
    mtile = 16 + (q & 15);
  }
  const unsigned short* A = Hcat + (size_t)mtile * 256 * FF;
  const float* B = (mtile < 16) ? (w2 + (size_t)(mtile >> 1) * (size_t)FF * DD) : rw2;
  unsigned short* Y = Ycat + (size_t)mtile * 256 * DD;
  int n0 = ntile * 128;

  __shared__ __align__(16) char Lc[98304];   // 96 KB: A 3x16K | B 3x16K
  const unsigned short* ldsS = (const unsigned short*)Lc;

  int tid = threadIdx.x, l = tid & 63, w = tid >> 6;
  int wm = w >> 2, wn = w & 3;               // wm2 x wn4
  int fr = l & 15, fq = l >> 4;
  int srow = l >> 2, soff = STG_CHUNK(l);
  int rdo = RD_OFF(fr, fq);

  const unsigned short* gA0 = A + (size_t)(w * 16 + srow) * FF + soff;
  const unsigned short* gA1 = A + (size_t)((8 + w) * 16 + srow) * FF + soff;
  int lrow = l >> 5;
  int kl0 = 2 * w + lrow;
  int kl1 = 16 + 2 * w + lrow;
  int cs0 = (l & 31) ^ (((kl0 >> 3) & 1) << 2);
  int cs1 = (l & 31) ^ (((kl1 >> 3) & 1) << 2);
  int nn0 = n0 + 4 * cs0;                     // max 1020 < DD: no clamp
  int nn1 = n0 + 4 * cs1;
  const float* gBa = B + (size_t)kl0 * DD + nn0;
  const float* gBb = B + (size_t)kl1 * DD + nn1;

  int cb2[2][4];
#pragma unroll
  for (int ni = 0; ni < 2; ++ni) {
    int base = fq * 4096 + ((((wn * 2 + ni) * 64 + fr * 4)) ^ ((fq & 1) << 6));
#pragma unroll
    for (int p = 0; p < 4; ++p) cb2[ni][p] = base + p * 1024;
  }

#define STG2(bb, hw) do { size_t ka = (size_t)(hw) * 32; size_t kb = ka * DD;   \
    GLDS16(gA0 + ka, Lc + (bb) * 16384 + w * 1024);                             \
    GLDS16(gA1 + ka, Lc + (bb) * 16384 + (8 + w) * 1024);                       \
    GLDS16(gBa + kb, Lc + 49152 + (bb) * 16384 + w * 1024);                     \
    GLDS16(gBb + kb, Lc + 49152 + (bb) * 16384 + (8 + w) * 1024); } while (0)

  f32x4 acc[8][2] = {};

  const int HN = 86;   // K halves (2752 / 32)
  STG2(0, 0);
  STG2(1, 1);

  for (int h = 0; h < HN; ++h) {
    int buf = h % 3;
    int hw = h + 2; if (hw >= HN) hw -= HN;
    int bufw = (buf + 2) % 3;

    asm volatile("s_waitcnt vmcnt(4)" ::: "memory");   // half h landed
    BAR();
    STG2(bufw, hw);

    const char* Bb = Lc + 49152 + buf * 16384;
    bf16x8 af[8];
#pragma unroll
    for (int mi = 0; mi < 8; ++mi)
      af[mi] = *(const bf16x8*)(ldsS + buf * 8192 + (wm * 8 + mi) * 512 + rdo);

    float fb[2][8];
#pragma unroll
    for (int ni = 0; ni < 2; ++ni)
#pragma unroll
      for (int p = 0; p < 4; ++p) {
        const char* bp = Bb + cb2[ni][p];
        fb[ni][2 * p]     = *(const float*)(bp);
        fb[ni][2 * p + 1] = *(const float*)(bp + 512);
      }
    __builtin_amdgcn_s_setprio(1);
#pragma unroll
    for (int ni = 0; ni < 2; ++ni) {
      union { bf16x8 h; unsigned int u[4]; } bu;
#pragma unroll
      for (int p = 0; p < 4; ++p)
        asm("v_cvt_pk_bf16_f32 %0, %1, %2" : "=v"(bu.u[p]) : "v"(fb[ni][2 * p]), "v"(fb[ni][2 * p + 1]));
#pragma unroll
      for (int mi = 0; mi < 8; ++mi)
        acc[mi][ni] = __builtin_amdgcn_mfma_f32_16x16x32_bf16(af[mi], bu.h, acc[mi][ni], 0, 0, 0);
    }
    __builtin_amdgcn_s_setprio(0);
  }
#undef STG2

#pragma unroll
  for (int mi = 0; mi < 8; ++mi)
#pragma unroll
    for (int ni = 0; ni < 2; ++ni)
#pragma unroll
      for (int r = 0; r < 4; ++r) {
        int gm = wm * 128 + mi * 16 + fq * 4 + r;
        int gn = n0 + (wn * 2 + ni) * 16 + fr;
        Y[(size_t)gm * DD + gn] = f2bf(acc[mi][ni][r]);
      }
}

// ---------------- combine ----------------------------------------
__global__ void combine_k(const unsigned short* __restrict__ Ye, const unsigned short* __restrict__ Yr,
                          const int* __restrict__ idx, const int* __restrict__ slot,
                          const float* __restrict__ gatev, const float* __restrict__ coef,
                          float* __restrict__ out) {
  int t = blockIdx.x, tid = threadIdx.x;
  int d = tid * 4;
  float c0 = coef[t * 2], c1 = coef[t * 2 + 1];
  int s = slot[t];
  float g = gatev[t] * c0;
  us4 vr = *(const us4*)(Yr + (size_t)t * DD + d);
  float4 o;
  if (s >= 0) {
    us4 ve = *(const us4*)(Ye + ((size_t)idx[t] * CC + s) * DD + d);
    o.x = g * bf2f(ve.x) + c1 * bf2f(vr.x);
    o.y = g * bf2f(ve.y) + c1 * bf2f(vr.y);
    o.z = g * bf2f(ve.z) + c1 * bf2f(vr.z);
    o.w = g * bf2f(ve.w) + c1 * bf2f(vr.w);
  } else {
    o.x = c1 * bf2f(vr.x);
    o.y = c1 * bf2f(vr.y);
    o.z = c1 * bf2f(vr.z);
    o.w = c1 * bf2f(vr.w);
  }
  *(float4*)(out + (size_t)t * DD + d) = o;
}

// ---------------- launch -----------------------------------------
extern "C" void kernel_launch(void* const* d_in, const int* in_sizes, int n_in,
                              void* d_out, int out_size, void* d_ws, size_t ws_size,
                              hipStream_t stream) {
  const float* x   = (const float*)d_in[0];
  const float* wg  = (const float*)d_in[1];
  const float* w1  = (const float*)d_in[2];
  const float* w3  = (const float*)d_in[3];
  const float* w2  = (const float*)d_in[4];
  const float* rw1 = (const float*)d_in[5];
  const float* rw3 = (const float*)d_in[6];
  const float* rw2 = (const float*)d_in[7];
  const float* cw  = (const float*)d_in[8];
  const float* cbv = (const float*)d_in[9];
  float* out = (float*)d_out;

  char* ws = (char*)d_ws;
  size_t o = 0;
  auto alloc = [&](size_t bytes) -> char* {
    char* p = ws + o; o = (o + bytes + 255) & ~(size_t)255; return p;
  };
  unsigned short* xe   = (unsigned short*)alloc((size_t)T_TOK * DD * 2);
  unsigned short* xb   = (unsigned short*)alloc((size_t)T_TOK * DD * 2);
  unsigned short* He   = (unsigned short*)alloc((size_t)T_TOK * FF * 2);
  unsigned short* Hr   = (unsigned short*)alloc((size_t)T_TOK * FF * 2);
  unsigned short* Ye   = (unsigned short*)alloc((size_t)T_TOK * DD * 2);
  unsigned short* Yr   = (unsigned short*)alloc((size_t)T_TOK * DD * 2);
  int*   idxp  = (int*)alloc(T_TOK * 4);
  float* gatev = (float*)alloc(T_TOK * 4);
  int*   slotp = (int*)alloc(T_TOK * 4);
  int*   tokp  = (int*)alloc(EE * CC * 4);
  float* coefp = (float*)alloc(T_TOK * 2 * 4);
  float* mep   = (float*)alloc(256);
  if (o > ws_size) return;

  zero_me_k<<<1, 64, 0, stream>>>(mep);
  gate_k<<<T_TOK / 4, 256, 0, stream>>>(x, wg, cw, cbv, idxp, gatev, coefp, mep);
  scan_k<<<1, 512, 0, stream>>>(idxp, mep, slotp, tokp, out + (size_t)T_TOK * DD);
  gather_k<<<2 * T_TOK, 256, 0, stream>>>(x, tokp, xb, xe);
  gemm1_k<<<704, 512, 0, stream>>>(xe, w1, w3, rw1, rw3, He);
  gemm2_k<<<256, 512, 0, stream>>>(He, w2, rw2, Ye);
  combine_k<<<T_TOK, 256, 0, stream>>>(Ye, Yr, idxp, slotp, gatev, coefp, out);
}

// Round 22
// 254.007 us; speedup vs baseline: 1.0644x; 1.0054x over previous
//
#include <hip/hip_runtime.h>
#include <hip/hip_bf16.h>
#include <stdint.h>

#define T_TOK 4096
#define DD 1024
#define EE 8
#define CC 512
#define FF 2752

typedef __attribute__((ext_vector_type(8))) short bf16x8;
typedef __attribute__((ext_vector_type(4))) float f32x4;
typedef __attribute__((ext_vector_type(4))) unsigned short us4;
typedef __attribute__((ext_vector_type(8))) unsigned short us8;

__device__ __forceinline__ float bf2f(unsigned short u) {
  union { float f; unsigned int i; } v; v.i = ((unsigned int)u) << 16; return v.f;
}
__device__ __forceinline__ unsigned short f2bf(float f) {
  union { float f; unsigned int i; } v; v.f = f;
  unsigned int r = v.i + 0x7fffu + ((v.i >> 16) & 1u);
  return (unsigned short)(r >> 16);
}

#define GLDS16(g, l) __builtin_amdgcn_global_load_lds( \
    (const __attribute__((address_space(1))) void*)(g), \
    (__attribute__((address_space(3))) void*)(l), 16, 0, 0)

// Verified swizzle (rounds 3-21) for bf16 fragment staging/reads.
#define STG_CHUNK(l) (((l & 3) ^ ((l >> 3) & 3)) * 8)
#define RD_OFF(fr, fq) ((fr) * 32 + (((fq) ^ (((fr) >> 1) & 3)) * 8))

#define BAR() do { asm volatile("" ::: "memory"); __builtin_amdgcn_s_barrier(); \
                   asm volatile("" ::: "memory"); } while (0)

__global__ void zero_me_k(float* me) { if (threadIdx.x < EE) me[threadIdx.x] = 0.0f; }

// ---------------- gating ----------------
__global__ void gate_k(const float* __restrict__ x, const float* __restrict__ wg,
                       const float* __restrict__ cw, const float* __restrict__ cbv,
                       int* __restrict__ idx, float* __restrict__ gatev,
                       float* __restrict__ coef, float* __restrict__ me_sum) {
  int tid = threadIdx.x, lane = tid & 63, wv = tid >> 6;
  int t = blockIdx.x * 4 + wv;
  const float* xr = x + (long)t * DD;
  float acc[EE] = {0,0,0,0,0,0,0,0};
  float c0 = 0.0f, c1 = 0.0f;
  for (int d = lane; d < DD; d += 64) {
    float xv = xr[d];
#pragma unroll
    for (int e = 0; e < EE; ++e) acc[e] += xv * wg[d * EE + e];
    c0 += xv * cw[d * 2 + 0];
    c1 += xv * cw[d * 2 + 1];
  }
#pragma unroll
  for (int o = 32; o > 0; o >>= 1) {
#pragma unroll
    for (int e = 0; e < EE; ++e) acc[e] += __shfl_xor(acc[e], o);
    c0 += __shfl_xor(c0, o);
    c1 += __shfl_xor(c1, o);
  }
  __shared__ float sme[EE];
  if (tid < EE) sme[tid] = 0.0f;
  __syncthreads();
  if (lane == 0) {
    float m = acc[0]; int am = 0;
#pragma unroll
    for (int e = 1; e < EE; ++e) if (acc[e] > m) { m = acc[e]; am = e; }
    float g[EE]; float s = 0.0f;
#pragma unroll
    for (int e = 0; e < EE; ++e) { g[e] = __expf(acc[e] - m); s += g[e]; }
    float inv = 1.0f / s;
    idx[t] = am;
    gatev[t] = g[am] * inv;
#pragma unroll
    for (int e = 0; e < EE; ++e) atomicAdd(&sme[e], g[e] * inv);
    float l0 = c0 + cbv[0], l1 = c1 + cbv[1];
    float mm = fmaxf(l0, l1);
    float e0 = __expf(l0 - mm), e1 = __expf(l1 - mm);
    float is = 1.0f / (e0 + e1);
    coef[t * 2 + 0] = e0 * is;
    coef[t * 2 + 1] = e1 * is;
  }
  __syncthreads();
  if (tid < EE) atomicAdd(&me_sum[tid], sme[tid]);
}

// ---------------- capacity scan ----------------
__global__ void scan_k(const int* __restrict__ idx, const float* __restrict__ me_sum,
                       int* __restrict__ slot, int* __restrict__ tok,
                       float* __restrict__ out_tail) {
  __shared__ int sidx[T_TOK];
  __shared__ int counts[EE];
  int tid = threadIdx.x;
  for (int i = tid; i < T_TOK; i += 512) sidx[i] = idx[i];
  __syncthreads();
  int e = tid >> 6, lane = tid & 63;
  int base = 0;
  for (int it = 0; it < T_TOK / 64; ++it) {
    int t = it * 64 + lane;
    bool f = (sidx[t] == e);
    unsigned long long m = __ballot(f);
    if (f) {
      int loc = base + __popcll(m & ((1ull << lane) - 1ull));
      slot[t] = (loc < CC) ? loc : -1;
      if (loc < CC) tok[e * CC + loc] = t;
    }
    base += __popcll(m);
  }
  if (lane == 0) counts[e] = base;
  __syncthreads();
  int filled = min(counts[e], CC);
  for (int c = filled + lane; c < CC; c += 64) tok[e * CC + c] = -1;
  if (tid == 0) {
    float la = 0.0f;
    for (int i = 0; i < EE; ++i) la += me_sum[i] * (float)counts[i];
    la *= (float)EE / ((float)T_TOK * (float)T_TOK);
    out_tail[0] = la;
    for (int i = 0; i < EE; ++i) out_tail[1 + i] = (float)counts[i];
  }
}

// ---------------- gather + bf16 convert ----------------
__global__ void gather_k(const float* __restrict__ x, const int* __restrict__ tok,
                         unsigned short* __restrict__ xb, unsigned short* __restrict__ xe) {
  int r = blockIdx.x, tid = threadIdx.x;
  int d = tid * 4;
  if (r < T_TOK) {
    float4 v = *(const float4*)(x + (long)r * DD + d);
    us4 o; o.x = f2bf(v.x); o.y = f2bf(v.y); o.z = f2bf(v.z); o.w = f2bf(v.w);
    *(us4*)(xb + (long)r * DD + d) = o;
  } else {
    int s = r - T_TOK;
    int t = tok[s];
    us4 o = {0, 0, 0, 0};
    if (t >= 0) {
      float4 v = *(const float4*)(x + (long)t * DD + d);
      o.x = f2bf(v.x); o.y = f2bf(v.y); o.z = f2bf(v.z); o.w = f2bf(v.w);
    }
    *(us4*)(xe + (long)s * DD + d) = o;
  }
}

// ---------------- GEMM1 (r12/r18 verified, best) -----------------
__global__ __launch_bounds__(512, 2)
void gemm1_k(const unsigned short* __restrict__ xcat,
             const float* __restrict__ w1, const float* __restrict__ w3,
             const float* __restrict__ rw1, const float* __restrict__ rw3,
             unsigned short* __restrict__ Hcat) {
  int lin = blockIdx.x;
  int work = (lin & 7) * 88 + (lin >> 3);     // 704 = 8 * 88
  int mtile, ntile;
  if (work < 352) {
    int e = work / 44, r = work - e * 44;
    ntile = r >> 1;
    mtile = e * 2 + (r & 1);
  } else {
    int q = work - 352;
    ntile = q >> 4;
    mtile = 16 + (q & 15);
  }
  const unsigned short* A = xcat + (size_t)mtile * 256 * DD;
  const float *B1, *B3;
  if (mtile < 16) { int e = mtile >> 1; B1 = w1 + (size_t)e * DD * FF; B3 = w3 + (size_t)e * DD * FF; }
  else { B1 = rw1; B3 = rw3; }
  unsigned short* H = Hcat + (size_t)mtile * 256 * FF;
  int n0 = ntile * 128;

  __shared__ __align__(16) char Lc[147456];   // 144 KB
  const unsigned short* ldsS = (const unsigned short*)Lc;

  int tid = threadIdx.x, l = tid & 63, w = tid >> 6;
  int wm = w >> 2, wn = w & 3;               // wm2 x wn4
  int fr = l & 15, fq = l >> 4;
  int srow = l >> 2, soff = STG_CHUNK(l);
  int rdo = RD_OFF(fr, fq);

  const unsigned short* gA0 = A + (size_t)(w * 16 + srow) * DD + soff;
  const unsigned short* gA1 = A + (size_t)((8 + w) * 16 + srow) * DD + soff;
  int lrow = l >> 5;
  int kl0 = 2 * w + lrow;
  int kl1 = 16 + 2 * w + lrow;
  int cs0 = (l & 31) ^ (((kl0 >> 3) & 1) << 2);
  int cs1 = (l & 31) ^ (((kl1 >> 3) & 1) << 2);
  int nn0 = n0 + 4 * cs0; if (nn0 >= FF) nn0 = 0;
  int nn1 = n0 + 4 * cs1; if (nn1 >= FF) nn1 = 0;
  const float* gB1a = B1 + (size_t)kl0 * FF + nn0;
  const float* gB1b = B1 + (size_t)kl1 * FF + nn1;
  const float* gB3a = B3 + (size_t)kl0 * FF + nn0;
  const float* gB3b = B3 + (size_t)kl1 * FF + nn1;

  int cb2[2][4];
#pragma unroll
  for (int ni = 0; ni < 2; ++ni) {
    int base = fq * 4096 + ((((wn * 2 + ni) * 64 + fr * 4)) ^ ((fq & 1) << 6));
#pragma unroll
    for (int p = 0; p < 4; ++p) cb2[ni][p] = base + p * 1024;
  }

#define STG1(bb, hw) do { size_t ka = (size_t)(hw) * 32; size_t kb = ka * FF;   \
    GLDS16(gA0 + ka, Lc + (bb) * 16384 + w * 1024);                             \
    GLDS16(gA1 + ka, Lc + (bb) * 16384 + (8 + w) * 1024);                       \
    GLDS16(gB1a + kb, Lc + 49152 + (bb) * 16384 + w * 1024);                    \
    GLDS16(gB1b + kb, Lc + 49152 + (bb) * 16384 + (8 + w) * 1024);              \
    GLDS16(gB3a + kb, Lc + 98304 + (bb) * 16384 + w * 1024);                    \
    GLDS16(gB3b + kb, Lc + 98304 + (bb) * 16384 + (8 + w) * 1024); } while (0)

  f32x4 acc1[8][2] = {};
  f32x4 acc3[8][2] = {};

  const int HN = 32;
  STG1(0, 0);
  STG1(1, 1);

  for (int h = 0; h < HN; ++h) {
    int buf = h % 3;
    int hw = h + 2; if (hw >= HN) hw -= HN;
    int bufw = (buf + 2) % 3;

    asm volatile("s_waitcnt vmcnt(6)" ::: "memory");
    BAR();
    STG1(bufw, hw);

    const char* Bb1 = Lc + 49152 + buf * 16384;
    const char* Bb3 = Lc + 98304 + buf * 16384;
    bf16x8 af[8];
#pragma unroll
    for (int mi = 0; mi < 8; ++mi)
      af[mi] = *(const bf16x8*)(ldsS + buf * 8192 + (wm * 8 + mi) * 512 + rdo);

    {
      float fb[2][8];
#pragma unroll
      for (int ni = 0; ni < 2; ++ni)
#pragma unroll
        for (int p = 0; p < 4; ++p) {
          const char* bp = Bb1 + cb2[ni][p];
          fb[ni][2 * p]     = *(const float*)(bp);
          fb[ni][2 * p + 1] = *(const float*)(bp + 512);
        }
      __builtin_amdgcn_s_setprio(1);
#pragma unroll
      for (int ni = 0; ni < 2; ++ni) {
        union { bf16x8 h; unsigned int u[4]; } bu;
#pragma unroll
        for (int p = 0; p < 4; ++p)
          asm("v_cvt_pk_bf16_f32 %0, %1, %2" : "=v"(bu.u[p]) : "v"(fb[ni][2 * p]), "v"(fb[ni][2 * p + 1]));
#pragma unroll
        for (int mi = 0; mi < 8; ++mi)
          acc1[mi][ni] = __builtin_amdgcn_mfma_f32_16x16x32_bf16(af[mi], bu.h, acc1[mi][ni], 0, 0, 0);
      }
      __builtin_amdgcn_s_setprio(0);
    }
    {
      float fb[2][8];
#pragma unroll
      for (int ni = 0; ni < 2; ++ni)
#pragma unroll
        for (int p = 0; p < 4; ++p) {
          const char* bp = Bb3 + cb2[ni][p];
          fb[ni][2 * p]     = *(const float*)(bp);
          fb[ni][2 * p + 1] = *(const float*)(bp + 512);
        }
      __builtin_amdgcn_s_setprio(1);
#pragma unroll
      for (int ni = 0; ni < 2; ++ni) {
        union { bf16x8 h; unsigned int u[4]; } bu;
#pragma unroll
        for (int p = 0; p < 4; ++p)
          asm("v_cvt_pk_bf16_f32 %0, %1, %2" : "=v"(bu.u[p]) : "v"(fb[ni][2 * p]), "v"(fb[ni][2 * p + 1]));
#pragma unroll
        for (int mi = 0; mi < 8; ++mi)
          acc3[mi][ni] = __builtin_amdgcn_mfma_f32_16x16x32_bf16(af[mi], bu.h, acc3[mi][ni], 0, 0, 0);
      }
      __builtin_amdgcn_s_setprio(0);
    }
  }
#undef STG1

#pragma unroll
  for (int mi = 0; mi < 8; ++mi)
#pragma unroll
    for (int ni = 0; ni < 2; ++ni)
#pragma unroll
      for (int r = 0; r < 4; ++r) {
        int gm = wm * 128 + mi * 16 + fq * 4 + r;
        int gn = n0 + (wn * 2 + ni) * 16 + fr;
        if (gn < FF) {
          float v1 = acc1[mi][ni][r], v3 = acc3[mi][ni][r];
          float h = v1 / (1.0f + __expf(-v1)) * v3;
          H[(size_t)gm * FF + gn] = f2bf(h);
        }
      }
}

// ---------------- GEMM2: Y = H @ W2, direct-f32 W2, 4-ring -------
// r21 structure with deeper pipeline: 4-buffer ring (128 KB), depth-3
// prefetch, vmcnt(8) (12 glds in flight, oldest stage of 4 drained).
// WAR safe: STG(h+3) targets buffer (h-1)%4 whose reads completed
// before BAR(h) (r17 proof).
__global__ __launch_bounds__(512, 2)
void gemm2_k(const unsigned short* __restrict__ Hcat,
             const float* __restrict__ w2, const float* __restrict__ rw2,
             unsigned short* __restrict__ Ycat) {
  int lin = blockIdx.x;
  int work = (lin & 7) * 32 + (lin >> 3);    // 256 = 8 * 32
  int mtile, ntile;
  if (work < 128) {
    int e = work >> 4, r = work & 15;
    ntile = r >> 1;
    mtile = e * 2 + (r & 1);
  } else {
    int q = work - 128;
    ntile = q >> 4;
    mtile = 16 + (q & 15);
  }
  const unsigned short* A = Hcat + (size_t)mtile * 256 * FF;
  const float* B = (mtile < 16) ? (w2 + (size_t)(mtile >> 1) * (size_t)FF * DD) : rw2;
  unsigned short* Y = Ycat + (size_t)mtile * 256 * DD;
  int n0 = ntile * 128;

  __shared__ __align__(16) char Lc[131072];  // 128 KB: A 4x16K | B 4x16K
  const unsigned short* ldsS = (const unsigned short*)Lc;

  int tid = threadIdx.x, l = tid & 63, w = tid >> 6;
  int wm = w >> 2, wn = w & 3;               // wm2 x wn4
  int fr = l & 15, fq = l >> 4;
  int srow = l >> 2, soff = STG_CHUNK(l);
  int rdo = RD_OFF(fr, fq);

  const unsigned short* gA0 = A + (size_t)(w * 16 + srow) * FF + soff;
  const unsigned short* gA1 = A + (size_t)((8 + w) * 16 + srow) * FF + soff;
  int lrow = l >> 5;
  int kl0 = 2 * w + lrow;
  int kl1 = 16 + 2 * w + lrow;
  int cs0 = (l & 31) ^ (((kl0 >> 3) & 1) << 2);
  int cs1 = (l & 31) ^ (((kl1 >> 3) & 1) << 2);
  int nn0 = n0 + 4 * cs0;                     // max 1020 < DD: no clamp
  int nn1 = n0 + 4 * cs1;
  const float* gBa = B + (size_t)kl0 * DD + nn0;
  const float* gBb = B + (size_t)kl1 * DD + nn1;

  int cb2[2][4];
#pragma unroll
  for (int ni = 0; ni < 2; ++ni) {
    int base = fq * 4096 + ((((wn * 2 + ni) * 64 + fr * 4)) ^ ((fq & 1) << 6));
#pragma unroll
    for (int p = 0; p < 4; ++p) cb2[ni][p] = base + p * 1024;
  }

#define STG2(bb, hw) do { size_t ka = (size_t)(hw) * 32; size_t kb = ka * DD;   \
    GLDS16(gA0 + ka, Lc + (bb) * 16384 + w * 1024);                             \
    GLDS16(gA1 + ka, Lc + (bb) * 16384 + (8 + w) * 1024);                       \
    GLDS16(gBa + kb, Lc + 65536 + (bb) * 16384 + w * 1024);                     \
    GLDS16(gBb + kb, Lc + 65536 + (bb) * 16384 + (8 + w) * 1024); } while (0)

  f32x4 acc[8][2] = {};

  const int HN = 86;   // K halves (2752 / 32)
  STG2(0, 0);
  STG2(1, 1);
  STG2(2, 2);

  for (int h = 0; h < HN; ++h) {
    int buf = h & 3;
    int hw = h + 3; if (hw >= HN) hw -= HN;
    int bufw = (buf + 3) & 3;

    asm volatile("s_waitcnt vmcnt(8)" ::: "memory");   // half h landed
    BAR();
    STG2(bufw, hw);

    const char* Bb = Lc + 65536 + buf * 16384;
    bf16x8 af[8];
#pragma unroll
    for (int mi = 0; mi < 8; ++mi)
      af[mi] = *(const bf16x8*)(ldsS + buf * 8192 + (wm * 8 + mi) * 512 + rdo);

    float fb[2][8];
#pragma unroll
    for (int ni = 0; ni < 2; ++ni)
#pragma unroll
      for (int p = 0; p < 4; ++p) {
        const char* bp = Bb + cb2[ni][p];
        fb[ni][2 * p]     = *(const float*)(bp);
        fb[ni][2 * p + 1] = *(const float*)(bp + 512);
      }
    __builtin_amdgcn_s_setprio(1);
#pragma unroll
    for (int ni = 0; ni < 2; ++ni) {
      union { bf16x8 h; unsigned int u[4]; } bu;
#pragma unroll
      for (int p = 0; p < 4; ++p)
        asm("v_cvt_pk_bf16_f32 %0, %1, %2" : "=v"(bu.u[p]) : "v"(fb[ni][2 * p]), "v"(fb[ni][2 * p + 1]));
#pragma unroll
      for (int mi = 0; mi < 8; ++mi)
        acc[mi][ni] = __builtin_amdgcn_mfma_f32_16x16x32_bf16(af[mi], bu.h, acc[mi][ni], 0, 0, 0);
    }
    __builtin_amdgcn_s_setprio(0);
  }
#undef STG2

#pragma unroll
  for (int mi = 0; mi < 8; ++mi)
#pragma unroll
    for (int ni = 0; ni < 2; ++ni)
#pragma unroll
      for (int r = 0; r < 4; ++r) {
        int gm = wm * 128 + mi * 16 + fq * 4 + r;
        int gn = n0 + (wn * 2 + ni) * 16 + fr;
        Y[(size_t)gm * DD + gn] = f2bf(acc[mi][ni][r]);
      }
}

// ---------------- combine ----------------------------------------
__global__ void combine_k(const unsigned short* __restrict__ Ye, const unsigned short* __restrict__ Yr,
                          const int* __restrict__ idx, const int* __restrict__ slot,
                          const float* __restrict__ gatev, const float* __restrict__ coef,
                          float* __restrict__ out) {
  int t = blockIdx.x, tid = threadIdx.x;
  int d = tid * 4;
  float c0 = coef[t * 2], c1 = coef[t * 2 + 1];
  int s = slot[t];
  float g = gatev[t] * c0;
  us4 vr = *(const us4*)(Yr + (size_t)t * DD + d);
  float4 o;
  if (s >= 0) {
    us4 ve = *(const us4*)(Ye + ((size_t)idx[t] * CC + s) * DD + d);
    o.x = g * bf2f(ve.x) + c1 * bf2f(vr.x);
    o.y = g * bf2f(ve.y) + c1 * bf2f(vr.y);
    o.z = g * bf2f(ve.z) + c1 * bf2f(vr.z);
    o.w = g * bf2f(ve.w) + c1 * bf2f(vr.w);
  } else {
    o.x = c1 * bf2f(vr.x);
    o.y = c1 * bf2f(vr.y);
    o.z = c1 * bf2f(vr.z);
    o.w = c1 * bf2f(vr.w);
  }
  *(float4*)(out + (size_t)t * DD + d) = o;
}

// ---------------- launch -----------------------------------------
extern "C" void kernel_launch(void* const* d_in, const int* in_sizes, int n_in,
                              void* d_out, int out_size, void* d_ws, size_t ws_size,
                              hipStream_t stream) {
  const float* x   = (const float*)d_in[0];
  const float* wg  = (const float*)d_in[1];
  const float* w1  = (const float*)d_in[2];
  const float* w3  = (const float*)d_in[3];
  const float* w2  = (const float*)d_in[4];
  const float* rw1 = (const float*)d_in[5];
  const float* rw3 = (const float*)d_in[6];
  const float* rw2 = (const float*)d_in[7];
  const float* cw  = (const float*)d_in[8];
  const float* cbv = (const float*)d_in[9];
  float* out = (float*)d_out;

  char* ws = (char*)d_ws;
  size_t o = 0;
  auto alloc = [&](size_t bytes) -> char* {
    char* p = ws + o; o = (o + bytes + 255) & ~(size_t)255; return p;
  };
  unsigned short* xe   = (unsigned short*)alloc((size_t)T_TOK * DD * 2);
  unsigned short* xb   = (unsigned short*)alloc((size_t)T_TOK * DD * 2);
  unsigned short* He   = (unsigned short*)alloc((size_t)T_TOK * FF * 2);
  unsigned short* Hr   = (unsigned short*)alloc((size_t)T_TOK * FF * 2);
  unsigned short* Ye   = (unsigned short*)alloc((size_t)T_TOK * DD * 2);
  unsigned short* Yr   = (unsigned short*)alloc((size_t)T_TOK * DD * 2);
  int*   idxp  = (int*)alloc(T_TOK * 4);
  float* gatev = (float*)alloc(T_TOK * 4);
  int*   slotp = (int*)alloc(T_TOK * 4);
  int*   tokp  = (int*)alloc(EE * CC * 4);
  float* coefp = (float*)alloc(T_TOK * 2 * 4);
  float* mep   = (float*)alloc(256);
  if (o > ws_size) return;

  zero_me_k<<<1, 64, 0, stream>>>(mep);
  gate_k<<<T_TOK / 4, 256, 0, stream>>>(x, wg, cw, cbv, idxp, gatev, coefp, mep);
  scan_k<<<1, 512, 0, stream>>>(idxp, mep, slotp, tokp, out + (size_t)T_TOK * DD);
  gather_k<<<2 * T_TOK, 256, 0, stream>>>(x, tokp, xb, xe);
  gemm1_k<<<704, 512, 0, stream>>>(xe, w1, w3, rw1, rw3, He);
  gemm2_k<<<256, 512, 0, stream>>>(He, w2, rw2, Ye);
  combine_k<<<T_TOK, 256, 0, stream>>>(Ye, Yr, idxp, slotp, gatev, coefp, out);
}